// Round 10
// baseline (569.382 us; speedup 1.0000x reference)
//
#include <hip/hip_runtime.h>
#include <hip/hip_bf16.h>

#define HW 9216      // 96*96

typedef unsigned short ushort;
typedef unsigned int   uint;
typedef __attribute__((ext_vector_type(4))) float f32x4;
typedef __attribute__((ext_vector_type(8))) short s16x8;

// ---------------- module-global intermediates (BSS) ----------------
__device__ float  g_p [8*4*32*HW];               // conv1 split-K partials
__device__ float  g_o1[4*32*HW];                 // conv1 out (bias+relu) fp32
__device__ float  g_q [2*4*26*HW];               // conv2 split-K partials (bias in kg0)
__device__ __align__(16) ushort g_a[36864*1248]; // M-matrix, bf16, MFMA A-frag swizzle
__device__ __align__(16) ushort g_b[18*39*512];  // weights,  bf16, MFMA B-frag swizzle
__device__ __align__(16) float  g_urv[2304*288*16]; // GEMM out, tile-major [pt][n][16px]

__device__ __forceinline__ ushort f2b(float f){  // fp32 -> bf16 bits, RNE
  uint x = __float_as_uint(f);
  return (ushort)((x + 0x7FFFu + ((x >> 16) & 1u)) >> 16);
}

// ---------------- K0: pack 1x1 weights into B-fragment swizzle
// K-ordering PERMUTED: k' = l*96 + c  (weight flat index = c*13 + l)
__global__ void pack_b_k(const float* __restrict__ uww, const float* __restrict__ rww,
                         const float* __restrict__ vww){
  int i = blockIdx.x*256 + threadIdx.x;
  if (i >= 3*96*1248) return;
  int gate = i / (96*1248); int rem = i % (96*1248);
  int oc = rem / 1248;      int kp = rem % 1248;   // k' position
  int l = kp / 96, c = kp % 96;
  const float* src = (gate == 0) ? uww : ((gate == 1) ? rww : vww);
  float v = src[oc*1248 + c*13 + l];
  int n  = gate*96 + oc;
  int nt = n >> 4, nl = n & 15;
  int kb = kp >> 5, kk = kp & 31;
  g_b[(nt*39 + kb)*512 + nl*32 + kk] = f2b(v);
}

// ---------------- K1: conv1 5x5 pad2 (104ch->32ch), split-K over 8 groups of 13 ch
__global__ __launch_bounds__(256) void conv1_k(const float* __restrict__ x,
                        const float* __restrict__ hp, const float* __restrict__ wt1){
  __shared__ __align__(16) float in_sh[13][20][24];
  __shared__ __align__(16) float w_sh[13][25][32];
  int tile = blockIdx.x;            // 0..35
  int kg   = blockIdx.y;            // 0..7
  int b    = blockIdx.z;
  int row0 = (tile / 6) * 16, col0 = (tile % 6) * 16;
  int t = threadIdx.x;

  for (int idx = t; idx < 13*20*24; idx += 256){
    int i = idx / 480, rem = idx % 480;
    int r = rem / 24, c = rem % 24;
    int gr = row0 + r - 2, gc = col0 + c - 2;
    float v = 0.f;
    if ((unsigned)gr < 96u && (unsigned)gc < 96u){
      int ci = kg*13 + i;
      v = (ci < 8) ? x[(b*8 + ci)*HW + gr*96 + gc]
                   : hp[(b*96 + ci - 8)*HW + gr*96 + gc];
    }
    in_sh[i][r][c] = v;
  }
  for (int idx = t; idx < 13*25*32; idx += 256){
    int i = idx / 800, rem = idx % 800;
    int tap = rem / 32, oc = rem % 32;
    int ci = kg*13 + i;
    w_sh[i][tap][oc] = wt1[oc*2600 + ci*25 + tap];
  }
  __syncthreads();

  int og  = t >> 5;
  int pos = t & 31;
  int row = pos >> 1, x0 = (pos & 1)*8;

  float acc[8][4];
  #pragma unroll
  for (int j = 0; j < 8; j++)
    #pragma unroll
    for (int o = 0; o < 4; o++) acc[j][o] = 0.f;

  for (int i = 0; i < 13; i++){
    #pragma unroll
    for (int ky = 0; ky < 5; ky++){
      const float* rp = &in_sh[i][row + ky][x0];
      f32x4 s0 = *(const f32x4*)(rp);
      f32x4 s1 = *(const f32x4*)(rp + 4);
      f32x4 s2 = *(const f32x4*)(rp + 8);
      float seg[12] = {s0.x,s0.y,s0.z,s0.w, s1.x,s1.y,s1.z,s1.w, s2.x,s2.y,s2.z,s2.w};
      #pragma unroll
      for (int kx = 0; kx < 5; kx++){
        f32x4 wv = *(const f32x4*)&w_sh[i][ky*5 + kx][og*4];
        #pragma unroll
        for (int j = 0; j < 8; j++){
          float a = seg[kx + j];
          acc[j][0] += a*wv.x; acc[j][1] += a*wv.y;
          acc[j][2] += a*wv.z; acc[j][3] += a*wv.w;
        }
      }
    }
  }

  float* dst = g_p + (size_t)kg*4*32*HW;
  int rg = row0 + row, cg = col0 + x0;
  #pragma unroll
  for (int o = 0; o < 4; o++){
    float* d = dst + ((size_t)(b*32 + og*4 + o))*HW + rg*96 + cg;
    #pragma unroll
    for (int j = 0; j < 8; j++) d[j] = acc[j][o];
  }
}

// ---------------- K2: combine conv1 partials + bias + relu
__global__ void combine1_k(const float* __restrict__ b1){
  int i = blockIdx.x*256 + threadIdx.x;
  int oc = (i / HW) & 31;
  float s = b1[oc];
  #pragma unroll
  for (int kg = 0; kg < 8; kg++) s += g_p[(size_t)kg*4*32*HW + i];
  g_o1[i] = fmaxf(s, 0.f);
}

// ---------------- K3: conv2 5x5 pad2 (32ch->26ch), split-K=2, bias in kg0; no relu
__global__ __launch_bounds__(256) void conv2_k(const float* __restrict__ wt2,
                                               const float* __restrict__ b2){
  __shared__ __align__(16) float in_sh[8][20][24];
  __shared__ __align__(16) float w_sh[8][25][32];
  int tile = blockIdx.x;
  int kg   = blockIdx.y;
  int b    = blockIdx.z;
  int row0 = (tile / 6) * 16, col0 = (tile % 6) * 16;
  int t = threadIdx.x;
  int og  = t >> 5;
  int pos = t & 31;
  int row = pos >> 1, x0 = (pos & 1)*8;

  float acc[8][4];
  #pragma unroll
  for (int j = 0; j < 8; j++)
    #pragma unroll
    for (int o = 0; o < 4; o++) acc[j][o] = 0.f;

  for (int cc = 0; cc < 2; cc++){
    __syncthreads();
    for (int idx = t; idx < 8*20*24; idx += 256){
      int i = idx / 480, rem = idx % 480;
      int r = rem / 24, c = rem % 24;
      int gr = row0 + r - 2, gc = col0 + c - 2;
      float v = 0.f;
      if ((unsigned)gr < 96u && (unsigned)gc < 96u){
        int ci = kg*16 + cc*8 + i;
        v = g_o1[(b*32 + ci)*HW + gr*96 + gc];
      }
      in_sh[i][r][c] = v;
    }
    for (int idx = t; idx < 8*25*32; idx += 256){
      int i = idx / 800, rem = idx % 800;
      int tap = rem / 32, oc = rem % 32;
      int ci = kg*16 + cc*8 + i;
      w_sh[i][tap][oc] = (oc < 26) ? wt2[oc*800 + ci*25 + tap] : 0.f;
    }
    __syncthreads();

    for (int i = 0; i < 8; i++){
      #pragma unroll
      for (int ky = 0; ky < 5; ky++){
        const float* rp = &in_sh[i][row + ky][x0];
        f32x4 s0 = *(const f32x4*)(rp);
        f32x4 s1 = *(const f32x4*)(rp + 4);
        f32x4 s2 = *(const f32x4*)(rp + 8);
        float seg[12] = {s0.x,s0.y,s0.z,s0.w, s1.x,s1.y,s1.z,s1.w, s2.x,s2.y,s2.z,s2.w};
        #pragma unroll
        for (int kx = 0; kx < 5; kx++){
          f32x4 wv = *(const f32x4*)&w_sh[i][ky*5 + kx][og*4];
          #pragma unroll
          for (int j = 0; j < 8; j++){
            float a = seg[kx + j];
            acc[j][0] += a*wv.x; acc[j][1] += a*wv.y;
            acc[j][2] += a*wv.z; acc[j][3] += a*wv.w;
          }
        }
      }
    }
  }

  int rg = row0 + row, cg = col0 + x0;
  #pragma unroll
  for (int o = 0; o < 4; o++){
    int slot = og*4 + o;
    if (slot < 26){
      float bias = (kg == 0) ? b2[slot] : 0.f;
      float* d = g_q + (size_t)kg*4*26*HW + ((size_t)(b*26 + slot))*HW + rg*96 + cg;
      #pragma unroll
      for (int j = 0; j < 8; j++) d[j] = acc[j][o] + bias;
    }
  }
}

// ---------------- K4: z-folded bilinear sampling -> A-matrix (bf16, A-frag swizzle)
// K-ordering k' = l*96 + c: each kb (32 k's) has ONE l -> corner wgts/offs live
// in registers per l-group; LDS layout [13][4][16] -> broadcast, no conflicts.
__global__ __launch_bounds__(256) void sample_k(const float* __restrict__ hp){
  __shared__ float cw[13][4][16];
  __shared__ int   co[13][4][16];
  int pt = blockIdx.x;            // 0..2303
  int t  = threadIdx.x;
  int b  = pt / 576;
  int p0 = (pt % 576) * 16;

  if (t < 208){
    int m = t/13, l = t%13;
    int p = p0 + m;
    const int NQ = 4*26*HW;
    float gx = fmaxf(g_q[(b*26 + l     )*HW + p] + g_q[NQ + (b*26 + l     )*HW + p], 0.f);
    float gy = fmaxf(g_q[(b*26 + 13 + l)*HW + p] + g_q[NQ + (b*26 + 13 + l)*HW + p], 0.f);
    float ix = gx * (96.f/95.f) - 0.5f;
    float iy = gy * (96.f/95.f) - 0.5f;
    float iz = (float)(l+1) * (13.f/12.f) - 0.5f;
    float z0 = floorf(iz);
    float zf = 0.f;
    #pragma unroll
    for (int dz = 0; dz < 2; dz++){
      float zc = z0 + (float)dz;
      float wz = 1.f - fabsf(iz - zc);
      if (zc >= 0.f && zc <= 12.f) zf += wz;
    }
    float x0f = floorf(ix), y0f = floorf(iy);
    #pragma unroll
    for (int dy = 0; dy < 2; dy++){
      float yc = y0f + (float)dy;
      float wy = 1.f - fabsf(iy - yc);
      bool  my = (yc >= 0.f) && (yc <= 95.f);
      int  yci = min(max((int)yc, 0), 95);
      #pragma unroll
      for (int dx = 0; dx < 2; dx++){
        float xc = x0f + (float)dx;
        float wx = 1.f - fabsf(ix - xc);
        bool  mx = (xc >= 0.f) && (xc <= 95.f);
        int  xci = min(max((int)xc, 0), 95);
        cw[l][dy*2+dx][m] = (mx && my) ? zf*wy*wx : 0.f;
        co[l][dy*2+dx][m] = yci*96 + xci;
      }
    }
  }
  __syncthreads();

  const float* hb = hp + b*96*HW;
  int m   = t & 15;               // pixel in low bits
  int kk0 = (t >> 4)*2;           // even channel-offset within 32-group
  uint* aout = (uint*)g_a;
  for (int l = 0; l < 13; l++){
    float w0 = cw[l][0][m], w1 = cw[l][1][m], w2 = cw[l][2][m], w3 = cw[l][3][m];
    int   o0 = co[l][0][m], o1 = co[l][1][m], o2 = co[l][2][m], o3 = co[l][3][m];
    #pragma unroll
    for (int kb3 = 0; kb3 < 3; kb3++){
      int c0 = kb3*32 + kk0;
      const float* pp0 = hb + c0*HW;
      const float* pp1 = pp0 + HW;
      float s0 = w0*pp0[o0] + w1*pp0[o1] + w2*pp0[o2] + w3*pp0[o3];
      float s1 = w0*pp1[o0] + w1*pp1[o1] + w2*pp1[o2] + w3*pp1[o3];
      int kb = l*3 + kb3;
      aout[(pt*39 + kb)*256 + m*16 + (kk0 >> 1)] = (uint)f2b(s0) | ((uint)f2b(s1) << 16);
    }
  }
}

// ---------------- K5: MFMA GEMM  [36864 x 1248] x [1248 x 288] -> g_urv (tile-major)
// LDS-staged B (4x less L2 traffic) + fully-unrolled acc (AGPRs, no scratch).
__global__ __launch_bounds__(256) void gemm_k(){
  __shared__ __align__(16) ushort Bsh[18*512];   // 18 KB: B[:,kb] tile
  int w    = threadIdx.x >> 6;
  int lane = threadIdx.x & 63;
  int pt   = blockIdx.x*4 + w;
  int nl   = lane & 15, quad = lane >> 4;
  int t    = threadIdx.x;

  f32x4 acc[18];
  #pragma unroll
  for (int nt = 0; nt < 18; nt++) acc[nt] = (f32x4){0.f,0.f,0.f,0.f};

  const s16x8* Ab = reinterpret_cast<const s16x8*>(g_a);
  const uint*  Bg = reinterpret_cast<const uint*>(g_b);
  uint* Bs32 = (uint*)Bsh;
  int foff = nl*4 + quad;

  for (int kb = 0; kb < 39; kb++){
    __syncthreads();
    #pragma unroll
    for (int u = 0; u < 18; u++){
      int idx = u*256 + t;
      Bs32[idx] = Bg[(idx >> 8)*39*256 + kb*256 + (idx & 255)];
    }
    __syncthreads();
    s16x8 a = Ab[(pt*39 + kb)*64 + foff];
    #pragma unroll
    for (int nt = 0; nt < 18; nt++){
      s16x8 bf = *(const s16x8*)&Bsh[nt*512 + nl*32 + quad*8];
      acc[nt] = __builtin_amdgcn_mfma_f32_16x16x32_bf16(a, bf, acc[nt], 0, 0, 0);
    }
  }

  // epilogue: tile-major, one f32x4 store per nt = 16 contiguous full 64B lines/wave
  float* dst = g_urv + (size_t)pt*4608;          // [pt][n=288][px=16]
  #pragma unroll
  for (int nt = 0; nt < 18; nt++)
    *(f32x4*)&dst[(nt*16 + nl)*16 + quad*4] = acc[nt];
}

// ---------------- K6: fused 3x3 convs on x + gating -> out
__global__ __launch_bounds__(256) void gate_k(const float* __restrict__ x,
                        const float* __restrict__ hp,
                        const float* __restrict__ uw, const float* __restrict__ ub,
                        const float* __restrict__ rw, const float* __restrict__ rb,
                        const float* __restrict__ vw, const float* __restrict__ vb,
                        const float* __restrict__ uwb, const float* __restrict__ rwb,
                        const float* __restrict__ vwb, float* __restrict__ out){
  int p  = blockIdx.x*256 + threadIdx.x;
  int oc = blockIdx.y;
  int b  = blockIdx.z;
  int h = p/96, w = p%96;
  float xU = ub[oc], xR = rb[oc], xV = vb[oc];
  const float* xb = x + b*8*HW;
  for (int ky = 0; ky < 3; ky++){
    int r = h+ky-1;
    if ((unsigned)r >= 96u) continue;
    for (int kx = 0; kx < 3; kx++){
      int c = w+kx-1;
      if ((unsigned)c >= 96u) continue;
      int off = r*96 + c;
      int wo  = ky*3 + kx;
      #pragma unroll
      for (int ic = 0; ic < 8; ic++){
        float a = xb[ic*HW + off];
        xU += a * uw[oc*72 + ic*9 + wo];
        xR += a * rw[oc*72 + ic*9 + wo];
        xV += a * vw[oc*72 + ic*9 + wo];
      }
    }
  }
  // read tile-major GEMM result
  int pt = b*576 + (p >> 4), px = p & 15;
  const float* ur = g_urv + (size_t)pt*4608 + px;
  float gU = ur[(0*96 + oc)*16] + uwb[oc];
  float gR = ur[(1*96 + oc)*16] + rwb[oc];
  float gV = ur[(2*96 + oc)*16] + vwb[oc];
  float u = 1.f / (1.f + __expf(-(xU + gU)));
  float r = 1.f / (1.f + __expf(-(xR + gR)));
  float v = xV + r * gV;
  float oi = (v >= 0.f) ? v : 0.2f*v;
  float h0 = hp[(b*96 + oc)*HW + p];
  out[(b*96 + oc)*HW + p] = h0*u + oi*(1.f - u);
}

extern "C" void kernel_launch(void* const* d_in, const int* in_sizes, int n_in,
                              void* d_out, int out_size, void* d_ws, size_t ws_size,
                              hipStream_t stream){
  const float* x    = (const float*)d_in[0];
  const float* hp   = (const float*)d_in[1];
  const float* sw1  = (const float*)d_in[2];
  const float* sb1  = (const float*)d_in[3];
  const float* sw2  = (const float*)d_in[4];
  const float* sb2  = (const float*)d_in[5];
  const float* rw   = (const float*)d_in[6];
  const float* rb   = (const float*)d_in[7];
  const float* uw   = (const float*)d_in[8];
  const float* ub   = (const float*)d_in[9];
  const float* vw   = (const float*)d_in[10];
  const float* vb   = (const float*)d_in[11];
  const float* rww  = (const float*)d_in[12];
  const float* rwb  = (const float*)d_in[13];
  const float* uww  = (const float*)d_in[14];
  const float* uwb  = (const float*)d_in[15];
  const float* vww  = (const float*)d_in[16];
  const float* vwb  = (const float*)d_in[17];

  pack_b_k  <<<dim3((3*96*1248 + 255)/256), dim3(256), 0, stream>>>(uww, rww, vww);
  conv1_k   <<<dim3(36, 8, 4), dim3(256), 0, stream>>>(x, hp, sw1);
  combine1_k<<<dim3(4*32*HW/256), dim3(256), 0, stream>>>(sb1);
  conv2_k   <<<dim3(36, 2, 4), dim3(256), 0, stream>>>(sw2, sb2);
  sample_k  <<<dim3(2304),     dim3(256), 0, stream>>>(hp);
  gemm_k    <<<dim3(576),      dim3(256), 0, stream>>>();
  gate_k    <<<dim3(36, 96, 4), dim3(256), 0, stream>>>(x, hp,
              uw, ub, rw, rb, vw, vb, uwb, rwb, vwb, (float*)d_out);
}

// Round 11
// 466.037 us; speedup vs baseline: 1.2218x; 1.2218x over previous
//
#include <hip/hip_runtime.h>
#include <hip/hip_bf16.h>

#define HW 9216      // 96*96

typedef unsigned short ushort;
typedef unsigned int   uint;
typedef __attribute__((ext_vector_type(4))) float f32x4;
typedef __attribute__((ext_vector_type(2))) uint  u32x2;
typedef __attribute__((ext_vector_type(8))) short s16x8;

// ---------------- module-global intermediates (BSS) ----------------
__device__ float  g_p [8*4*32*HW];               // conv1 split-K partials
__device__ float  g_o1[4*32*HW];                 // conv1 out (bias+relu) fp32
__device__ float  g_q [2*4*26*HW];               // conv2 split-K partials (bias in kg0)
__device__ __align__(16) float g_ht[4*HW*96];    // hp transposed: [b][spatial][c]
__device__ __align__(16) ushort g_a[36864*1248]; // M-matrix, bf16, MFMA A-frag swizzle
__device__ __align__(16) ushort g_b[18*39*512];  // weights,  bf16, MFMA B-frag swizzle
__device__ __align__(16) float  g_urv[2304*288*16]; // GEMM out, tile-major [pt][n][16px]

__device__ __forceinline__ ushort f2b(float f){  // fp32 -> bf16 bits, RNE
  uint x = __float_as_uint(f);
  return (ushort)((x + 0x7FFFu + ((x >> 16) & 1u)) >> 16);
}

// ---------------- K0: pack 1x1 weights into B-fragment swizzle
// K-ordering PERMUTED: k' = l*96 + c  (weight flat index = c*13 + l)
__global__ void pack_b_k(const float* __restrict__ uww, const float* __restrict__ rww,
                         const float* __restrict__ vww){
  int i = blockIdx.x*256 + threadIdx.x;
  if (i >= 3*96*1248) return;
  int gate = i / (96*1248); int rem = i % (96*1248);
  int oc = rem / 1248;      int kp = rem % 1248;   // k' position
  int l = kp / 96, c = kp % 96;
  const float* src = (gate == 0) ? uww : ((gate == 1) ? rww : vww);
  float v = src[oc*1248 + c*13 + l];
  int n  = gate*96 + oc;
  int nt = n >> 4, nl = n & 15;
  int kb = kp >> 5, kk = kp & 31;
  g_b[(nt*39 + kb)*512 + nl*32 + kk] = f2b(v);
}

// ---------------- K0b: transpose hp (B,C,HW) -> g_ht (B,HW,C)
__global__ __launch_bounds__(256) void transpose_k(const float* __restrict__ hp){
  __shared__ float tile[32][33];
  int s0 = blockIdx.x*32;          // spatial tile
  int c0 = blockIdx.y*32;          // channel tile (96 = 3*32)
  int b  = blockIdx.z;
  int t  = threadIdx.x;
  for (int i = t; i < 32*32; i += 256){
    int c = i >> 5, s = i & 31;
    tile[c][s] = hp[((size_t)(b*96 + c0 + c))*HW + s0 + s];
  }
  __syncthreads();
  for (int i = t; i < 32*32; i += 256){
    int s = i >> 5, c = i & 31;
    g_ht[((size_t)b*HW + s0 + s)*96 + c0 + c] = tile[c][s];
  }
}

// ---------------- K1: conv1 5x5 pad2 (104ch->32ch), split-K over 8 groups of 13 ch
__global__ __launch_bounds__(256) void conv1_k(const float* __restrict__ x,
                        const float* __restrict__ hp, const float* __restrict__ wt1){
  __shared__ __align__(16) float in_sh[13][20][24];
  __shared__ __align__(16) float w_sh[13][25][32];
  int tile = blockIdx.x;            // 0..35
  int kg   = blockIdx.y;            // 0..7
  int b    = blockIdx.z;
  int row0 = (tile / 6) * 16, col0 = (tile % 6) * 16;
  int t = threadIdx.x;

  for (int idx = t; idx < 13*20*24; idx += 256){
    int i = idx / 480, rem = idx % 480;
    int r = rem / 24, c = rem % 24;
    int gr = row0 + r - 2, gc = col0 + c - 2;
    float v = 0.f;
    if ((unsigned)gr < 96u && (unsigned)gc < 96u){
      int ci = kg*13 + i;
      v = (ci < 8) ? x[(b*8 + ci)*HW + gr*96 + gc]
                   : hp[(b*96 + ci - 8)*HW + gr*96 + gc];
    }
    in_sh[i][r][c] = v;
  }
  for (int idx = t; idx < 13*25*32; idx += 256){
    int i = idx / 800, rem = idx % 800;
    int tap = rem / 32, oc = rem % 32;
    int ci = kg*13 + i;
    w_sh[i][tap][oc] = wt1[oc*2600 + ci*25 + tap];
  }
  __syncthreads();

  int og  = t >> 5;
  int pos = t & 31;
  int row = pos >> 1, x0 = (pos & 1)*8;

  float acc[8][4];
  #pragma unroll
  for (int j = 0; j < 8; j++)
    #pragma unroll
    for (int o = 0; o < 4; o++) acc[j][o] = 0.f;

  for (int i = 0; i < 13; i++){
    #pragma unroll
    for (int ky = 0; ky < 5; ky++){
      const float* rp = &in_sh[i][row + ky][x0];
      f32x4 s0 = *(const f32x4*)(rp);
      f32x4 s1 = *(const f32x4*)(rp + 4);
      f32x4 s2 = *(const f32x4*)(rp + 8);
      float seg[12] = {s0.x,s0.y,s0.z,s0.w, s1.x,s1.y,s1.z,s1.w, s2.x,s2.y,s2.z,s2.w};
      #pragma unroll
      for (int kx = 0; kx < 5; kx++){
        f32x4 wv = *(const f32x4*)&w_sh[i][ky*5 + kx][og*4];
        #pragma unroll
        for (int j = 0; j < 8; j++){
          float a = seg[kx + j];
          acc[j][0] += a*wv.x; acc[j][1] += a*wv.y;
          acc[j][2] += a*wv.z; acc[j][3] += a*wv.w;
        }
      }
    }
  }

  float* dst = g_p + (size_t)kg*4*32*HW;
  int rg = row0 + row, cg = col0 + x0;
  #pragma unroll
  for (int o = 0; o < 4; o++){
    float* d = dst + ((size_t)(b*32 + og*4 + o))*HW + rg*96 + cg;
    #pragma unroll
    for (int j = 0; j < 8; j++) d[j] = acc[j][o];
  }
}

// ---------------- K2: combine conv1 partials + bias + relu
__global__ void combine1_k(const float* __restrict__ b1){
  int i = blockIdx.x*256 + threadIdx.x;
  int oc = (i / HW) & 31;
  float s = b1[oc];
  #pragma unroll
  for (int kg = 0; kg < 8; kg++) s += g_p[(size_t)kg*4*32*HW + i];
  g_o1[i] = fmaxf(s, 0.f);
}

// ---------------- K3: conv2 5x5 pad2 (32ch->26ch), split-K=2, bias in kg0; no relu
__global__ __launch_bounds__(256) void conv2_k(const float* __restrict__ wt2,
                                               const float* __restrict__ b2){
  __shared__ __align__(16) float in_sh[8][20][24];
  __shared__ __align__(16) float w_sh[8][25][32];
  int tile = blockIdx.x;
  int kg   = blockIdx.y;
  int b    = blockIdx.z;
  int row0 = (tile / 6) * 16, col0 = (tile % 6) * 16;
  int t = threadIdx.x;
  int og  = t >> 5;
  int pos = t & 31;
  int row = pos >> 1, x0 = (pos & 1)*8;

  float acc[8][4];
  #pragma unroll
  for (int j = 0; j < 8; j++)
    #pragma unroll
    for (int o = 0; o < 4; o++) acc[j][o] = 0.f;

  for (int cc = 0; cc < 2; cc++){
    __syncthreads();
    for (int idx = t; idx < 8*20*24; idx += 256){
      int i = idx / 480, rem = idx % 480;
      int r = rem / 24, c = rem % 24;
      int gr = row0 + r - 2, gc = col0 + c - 2;
      float v = 0.f;
      if ((unsigned)gr < 96u && (unsigned)gc < 96u){
        int ci = kg*16 + cc*8 + i;
        v = g_o1[(b*32 + ci)*HW + gr*96 + gc];
      }
      in_sh[i][r][c] = v;
    }
    for (int idx = t; idx < 8*25*32; idx += 256){
      int i = idx / 800, rem = idx % 800;
      int tap = rem / 32, oc = rem % 32;
      int ci = kg*16 + cc*8 + i;
      w_sh[i][tap][oc] = (oc < 26) ? wt2[oc*800 + ci*25 + tap] : 0.f;
    }
    __syncthreads();

    for (int i = 0; i < 8; i++){
      #pragma unroll
      for (int ky = 0; ky < 5; ky++){
        const float* rp = &in_sh[i][row + ky][x0];
        f32x4 s0 = *(const f32x4*)(rp);
        f32x4 s1 = *(const f32x4*)(rp + 4);
        f32x4 s2 = *(const f32x4*)(rp + 8);
        float seg[12] = {s0.x,s0.y,s0.z,s0.w, s1.x,s1.y,s1.z,s1.w, s2.x,s2.y,s2.z,s2.w};
        #pragma unroll
        for (int kx = 0; kx < 5; kx++){
          f32x4 wv = *(const f32x4*)&w_sh[i][ky*5 + kx][og*4];
          #pragma unroll
          for (int j = 0; j < 8; j++){
            float a = seg[kx + j];
            acc[j][0] += a*wv.x; acc[j][1] += a*wv.y;
            acc[j][2] += a*wv.z; acc[j][3] += a*wv.w;
          }
        }
      }
    }
  }

  int rg = row0 + row, cg = col0 + x0;
  #pragma unroll
  for (int o = 0; o < 4; o++){
    int slot = og*4 + o;
    if (slot < 26){
      float bias = (kg == 0) ? b2[slot] : 0.f;
      float* d = g_q + (size_t)kg*4*26*HW + ((size_t)(b*26 + slot))*HW + rg*96 + cg;
      #pragma unroll
      for (int j = 0; j < 8; j++) d[j] = acc[j][o] + bias;
    }
  }
}

// ---------------- K4: z-folded bilinear sampling -> A-matrix (bf16, A-frag swizzle)
// Channel-contiguous gathers from g_ht: thread = (px m, channel-quad cq).
// One f32x4 load serves 4 channels of one corner. k' = l*96 + c ordering.
__global__ __launch_bounds__(384) void sample_k(){
  __shared__ float cw[13][4][16];
  __shared__ int   co[13][4][16];
  int pt = blockIdx.x;            // 0..2303
  int t  = threadIdx.x;           // 0..383
  int b  = pt / 576;
  int p0 = (pt % 576) * 16;

  if (t < 208){
    int m = t/13, l = t%13;
    int p = p0 + m;
    const int NQ = 4*26*HW;
    float gx = fmaxf(g_q[(b*26 + l     )*HW + p] + g_q[NQ + (b*26 + l     )*HW + p], 0.f);
    float gy = fmaxf(g_q[(b*26 + 13 + l)*HW + p] + g_q[NQ + (b*26 + 13 + l)*HW + p], 0.f);
    float ix = gx * (96.f/95.f) - 0.5f;
    float iy = gy * (96.f/95.f) - 0.5f;
    float iz = (float)(l+1) * (13.f/12.f) - 0.5f;
    float z0 = floorf(iz);
    float zf = 0.f;
    #pragma unroll
    for (int dz = 0; dz < 2; dz++){
      float zc = z0 + (float)dz;
      float wz = 1.f - fabsf(iz - zc);
      if (zc >= 0.f && zc <= 12.f) zf += wz;
    }
    float x0f = floorf(ix), y0f = floorf(iy);
    #pragma unroll
    for (int dy = 0; dy < 2; dy++){
      float yc = y0f + (float)dy;
      float wy = 1.f - fabsf(iy - yc);
      bool  my = (yc >= 0.f) && (yc <= 95.f);
      int  yci = min(max((int)yc, 0), 95);
      #pragma unroll
      for (int dx = 0; dx < 2; dx++){
        float xc = x0f + (float)dx;
        float wx = 1.f - fabsf(ix - xc);
        bool  mx = (xc >= 0.f) && (xc <= 95.f);
        int  xci = min(max((int)xc, 0), 95);
        cw[l][dy*2+dx][m] = (mx && my) ? zf*wy*wx : 0.f;
        co[l][dy*2+dx][m] = yci*96 + xci;
      }
    }
  }
  __syncthreads();

  int m  = t & 15;                 // pixel in tile (lanes 0-15)
  int cq = t >> 4;                 // channel quad 0..23 (c0 = cq*4)
  int c0 = cq*4;
  const float* hb = g_ht + (size_t)b*HW*96 + c0;
  int kb3 = cq >> 3;               // which 32-block within l
  int kk  = (cq & 7)*4;            // offset within 32-block
  for (int l = 0; l < 13; l++){
    float w0 = cw[l][0][m], w1 = cw[l][1][m], w2 = cw[l][2][m], w3 = cw[l][3][m];
    int   o0 = co[l][0][m], o1 = co[l][1][m], o2 = co[l][2][m], o3 = co[l][3][m];
    f32x4 v0 = *(const f32x4*)(hb + (size_t)o0*96);
    f32x4 v1 = *(const f32x4*)(hb + (size_t)o1*96);
    f32x4 v2 = *(const f32x4*)(hb + (size_t)o2*96);
    f32x4 v3 = *(const f32x4*)(hb + (size_t)o3*96);
    f32x4 acc = w0*v0 + w1*v1 + w2*v2 + w3*v3;
    int kb = l*3 + kb3;
    u32x2 pk;
    pk.x = (uint)f2b(acc.x) | ((uint)f2b(acc.y) << 16);
    pk.y = (uint)f2b(acc.z) | ((uint)f2b(acc.w) << 16);
    *(u32x2*)&g_a[(size_t)(pt*39 + kb)*512 + m*32 + kk] = pk;
  }
}

// ---------------- K5: MFMA GEMM  [36864 x 1248] x [1248 x 288] -> g_urv (tile-major)
// LDS-staged B (4x less L2 traffic) + fully-unrolled acc (AGPRs, no scratch).
__global__ __launch_bounds__(256) void gemm_k(){
  __shared__ __align__(16) ushort Bsh[18*512];   // 18 KB: B[:,kb] tile
  int w    = threadIdx.x >> 6;
  int lane = threadIdx.x & 63;
  int pt   = blockIdx.x*4 + w;
  int nl   = lane & 15, quad = lane >> 4;
  int t    = threadIdx.x;

  f32x4 acc[18];
  #pragma unroll
  for (int nt = 0; nt < 18; nt++) acc[nt] = (f32x4){0.f,0.f,0.f,0.f};

  const s16x8* Ab = reinterpret_cast<const s16x8*>(g_a);
  const uint*  Bg = reinterpret_cast<const uint*>(g_b);
  uint* Bs32 = (uint*)Bsh;
  int foff = nl*4 + quad;

  for (int kb = 0; kb < 39; kb++){
    __syncthreads();
    #pragma unroll
    for (int u = 0; u < 18; u++){
      int idx = u*256 + t;
      Bs32[idx] = Bg[(idx >> 8)*39*256 + kb*256 + (idx & 255)];
    }
    __syncthreads();
    s16x8 a = Ab[(pt*39 + kb)*64 + foff];
    #pragma unroll
    for (int nt = 0; nt < 18; nt++){
      s16x8 bf = *(const s16x8*)&Bsh[nt*512 + nl*32 + quad*8];
      acc[nt] = __builtin_amdgcn_mfma_f32_16x16x32_bf16(a, bf, acc[nt], 0, 0, 0);
    }
  }

  // epilogue: tile-major, one f32x4 store per nt = 16 contiguous full 64B lines/wave
  float* dst = g_urv + (size_t)pt*4608;          // [pt][n=288][px=16]
  #pragma unroll
  for (int nt = 0; nt < 18; nt++)
    *(f32x4*)&dst[(nt*16 + nl)*16 + quad*4] = acc[nt];
}

// ---------------- K6: fused 3x3 convs on x + gating -> out
__global__ __launch_bounds__(256) void gate_k(const float* __restrict__ x,
                        const float* __restrict__ hp,
                        const float* __restrict__ uw, const float* __restrict__ ub,
                        const float* __restrict__ rw, const float* __restrict__ rb,
                        const float* __restrict__ vw, const float* __restrict__ vb,
                        const float* __restrict__ uwb, const float* __restrict__ rwb,
                        const float* __restrict__ vwb, float* __restrict__ out){
  int p  = blockIdx.x*256 + threadIdx.x;
  int oc = blockIdx.y;
  int b  = blockIdx.z;
  int h = p/96, w = p%96;
  float xU = ub[oc], xR = rb[oc], xV = vb[oc];
  const float* xb = x + b*8*HW;
  for (int ky = 0; ky < 3; ky++){
    int r = h+ky-1;
    if ((unsigned)r >= 96u) continue;
    for (int kx = 0; kx < 3; kx++){
      int c = w+kx-1;
      if ((unsigned)c >= 96u) continue;
      int off = r*96 + c;
      int wo  = ky*3 + kx;
      #pragma unroll
      for (int ic = 0; ic < 8; ic++){
        float a = xb[ic*HW + off];
        xU += a * uw[oc*72 + ic*9 + wo];
        xR += a * rw[oc*72 + ic*9 + wo];
        xV += a * vw[oc*72 + ic*9 + wo];
      }
    }
  }
  // read tile-major GEMM result
  int pt = b*576 + (p >> 4), px = p & 15;
  const float* ur = g_urv + (size_t)pt*4608 + px;
  float gU = ur[(0*96 + oc)*16] + uwb[oc];
  float gR = ur[(1*96 + oc)*16] + rwb[oc];
  float gV = ur[(2*96 + oc)*16] + vwb[oc];
  float u = 1.f / (1.f + __expf(-(xU + gU)));
  float r = 1.f / (1.f + __expf(-(xR + gR)));
  float v = xV + r * gV;
  float oi = (v >= 0.f) ? v : 0.2f*v;
  float h0 = hp[(b*96 + oc)*HW + p];
  out[(b*96 + oc)*HW + p] = h0*u + oi*(1.f - u);
}

extern "C" void kernel_launch(void* const* d_in, const int* in_sizes, int n_in,
                              void* d_out, int out_size, void* d_ws, size_t ws_size,
                              hipStream_t stream){
  const float* x    = (const float*)d_in[0];
  const float* hp   = (const float*)d_in[1];
  const float* sw1  = (const float*)d_in[2];
  const float* sb1  = (const float*)d_in[3];
  const float* sw2  = (const float*)d_in[4];
  const float* sb2  = (const float*)d_in[5];
  const float* rw   = (const float*)d_in[6];
  const float* rb   = (const float*)d_in[7];
  const float* uw   = (const float*)d_in[8];
  const float* ub   = (const float*)d_in[9];
  const float* vw   = (const float*)d_in[10];
  const float* vb   = (const float*)d_in[11];
  const float* rww  = (const float*)d_in[12];
  const float* rwb  = (const float*)d_in[13];
  const float* uww  = (const float*)d_in[14];
  const float* uwb  = (const float*)d_in[15];
  const float* vww  = (const float*)d_in[16];
  const float* vwb  = (const float*)d_in[17];

  pack_b_k   <<<dim3((3*96*1248 + 255)/256), dim3(256), 0, stream>>>(uww, rww, vww);
  transpose_k<<<dim3(288, 3, 4), dim3(256), 0, stream>>>(hp);
  conv1_k    <<<dim3(36, 8, 4), dim3(256), 0, stream>>>(x, hp, sw1);
  combine1_k <<<dim3(4*32*HW/256), dim3(256), 0, stream>>>(sb1);
  conv2_k    <<<dim3(36, 2, 4), dim3(256), 0, stream>>>(sw2, sb2);
  sample_k   <<<dim3(2304),     dim3(384), 0, stream>>>();
  gemm_k     <<<dim3(576),      dim3(256), 0, stream>>>();
  gate_k     <<<dim3(36, 96, 4), dim3(256), 0, stream>>>(x, hp,
               uw, ub, rw, rb, vw, vb, uwb, rwb, vwb, (float*)d_out);
}

// Round 12
// 444.701 us; speedup vs baseline: 1.2804x; 1.0480x over previous
//
#include <hip/hip_runtime.h>
#include <hip/hip_bf16.h>

#define HW 9216      // 96*96

typedef unsigned short ushort;
typedef unsigned int   uint;
typedef __attribute__((ext_vector_type(4))) float f32x4;
typedef __attribute__((ext_vector_type(2))) uint  u32x2;
typedef __attribute__((ext_vector_type(8))) short s16x8;

// ---------------- module-global intermediates (BSS) ----------------
__device__ float  g_p [8*4*32*HW];               // conv1 split-K partials
__device__ float  g_o1[4*32*HW];                 // conv1 out (bias+relu) fp32
__device__ float  g_q [2*4*26*HW];               // conv2 split-K partials (bias in kg0)
__device__ __align__(16) float g_w1p[104*25*32]; // conv1 weights repacked [ci][tap][oc]
__device__ __align__(16) float g_ht[4*HW*96];    // hp transposed: [b][spatial][c]
__device__ __align__(16) ushort g_a[36864*1248]; // M-matrix, bf16, MFMA A-frag swizzle
__device__ __align__(16) ushort g_b[18*39*512];  // weights,  bf16, MFMA B-frag swizzle
__device__ __align__(16) float  g_urv[2304*288*16]; // GEMM out, tile-major [pt][n][16px]

__device__ __forceinline__ ushort f2b(float f){  // fp32 -> bf16 bits, RNE
  uint x = __float_as_uint(f);
  return (ushort)((x + 0x7FFFu + ((x >> 16) & 1u)) >> 16);
}

// ---------------- K0: pack 1x1 weights into B-fragment swizzle
// K-ordering PERMUTED: k' = l*96 + c  (weight flat index = c*13 + l)
__global__ void pack_b_k(const float* __restrict__ uww, const float* __restrict__ rww,
                         const float* __restrict__ vww){
  int i = blockIdx.x*256 + threadIdx.x;
  if (i >= 3*96*1248) return;
  int gate = i / (96*1248); int rem = i % (96*1248);
  int oc = rem / 1248;      int kp = rem % 1248;   // k' position
  int l = kp / 96, c = kp % 96;
  const float* src = (gate == 0) ? uww : ((gate == 1) ? rww : vww);
  float v = src[oc*1248 + c*13 + l];
  int n  = gate*96 + oc;
  int nt = n >> 4, nl = n & 15;
  int kb = kp >> 5, kk = kp & 31;
  g_b[(nt*39 + kb)*512 + nl*32 + kk] = f2b(v);
}

// ---------------- K0a: repack conv1 weights (32,104,25) -> [ci][tap][oc]
__global__ void pack_w1_k(const float* __restrict__ wt1){
  int i = blockIdx.x*256 + threadIdx.x;
  if (i >= 104*25*32) return;
  int oc = i / 2600; int rem = i % 2600;
  int ci = rem / 25; int tap = rem % 25;
  g_w1p[(ci*25 + tap)*32 + oc] = wt1[i];
}

// ---------------- K0b: transpose hp (B,C,HW) -> g_ht (B,HW,C)
__global__ __launch_bounds__(256) void transpose_k(const float* __restrict__ hp){
  __shared__ float tile[32][33];
  int s0 = blockIdx.x*32;          // spatial tile
  int c0 = blockIdx.y*32;          // channel tile (96 = 3*32)
  int b  = blockIdx.z;
  int t  = threadIdx.x;
  for (int i = t; i < 32*32; i += 256){
    int c = i >> 5, s = i & 31;
    tile[c][s] = hp[((size_t)(b*96 + c0 + c))*HW + s0 + s];
  }
  __syncthreads();
  for (int i = t; i < 32*32; i += 256){
    int s = i >> 5, c = i & 31;
    g_ht[((size_t)b*HW + s0 + s)*96 + c0 + c] = tile[c][s];
  }
}

// ---------------- K1: conv1 5x5 pad2 (104ch->32ch), split-K over 8 groups of 13 ch
// Weights via broadcast f32x4 global loads (L1-hot); LDS = input tile only.
__global__ __launch_bounds__(256) void conv1_k(const float* __restrict__ x,
                        const float* __restrict__ hp){
  __shared__ __align__(16) float in_sh[13][20][28]; // 29.1 KB, stride 28 (2-way = free)
  int tile = blockIdx.x;            // 0..35
  int kg   = blockIdx.y;            // 0..7
  int b    = blockIdx.z;
  int row0 = (tile / 6) * 16, col0 = (tile % 6) * 16;
  int t = threadIdx.x;

  for (int idx = t; idx < 13*20*24; idx += 256){
    int i = idx / 480, rem = idx % 480;
    int r = rem / 24, c = rem % 24;
    int gr = row0 + r - 2, gc = col0 + c - 2;
    float v = 0.f;
    if ((unsigned)gr < 96u && (unsigned)gc < 96u){
      int ci = kg*13 + i;
      v = (ci < 8) ? x[(b*8 + ci)*HW + gr*96 + gc]
                   : hp[(b*96 + ci - 8)*HW + gr*96 + gc];
    }
    in_sh[i][r][c] = v;
  }
  __syncthreads();

  int og  = t >> 5;
  int pos = t & 31;
  int row = pos >> 1, x0 = (pos & 1)*8;

  float acc[8][4];
  #pragma unroll
  for (int j = 0; j < 8; j++)
    #pragma unroll
    for (int o = 0; o < 4; o++) acc[j][o] = 0.f;

  for (int i = 0; i < 13; i++){
    const float* wbase = g_w1p + (size_t)(kg*13 + i)*800 + og*4;
    #pragma unroll
    for (int ky = 0; ky < 5; ky++){
      const float* rp = &in_sh[i][row + ky][x0];
      f32x4 s0 = *(const f32x4*)(rp);
      f32x4 s1 = *(const f32x4*)(rp + 4);
      f32x4 s2 = *(const f32x4*)(rp + 8);
      float seg[12] = {s0.x,s0.y,s0.z,s0.w, s1.x,s1.y,s1.z,s1.w, s2.x,s2.y,s2.z,s2.w};
      #pragma unroll
      for (int kx = 0; kx < 5; kx++){
        f32x4 wv = *(const f32x4*)(wbase + (ky*5 + kx)*32);
        #pragma unroll
        for (int j = 0; j < 8; j++){
          float a = seg[kx + j];
          acc[j][0] += a*wv.x; acc[j][1] += a*wv.y;
          acc[j][2] += a*wv.z; acc[j][3] += a*wv.w;
        }
      }
    }
  }

  float* dst = g_p + (size_t)kg*4*32*HW;
  int rg = row0 + row, cg = col0 + x0;
  #pragma unroll
  for (int o = 0; o < 4; o++){
    float* d = dst + ((size_t)(b*32 + og*4 + o))*HW + rg*96 + cg;
    #pragma unroll
    for (int j = 0; j < 8; j++) d[j] = acc[j][o];
  }
}

// ---------------- K2: combine conv1 partials + bias + relu
__global__ void combine1_k(const float* __restrict__ b1){
  int i = blockIdx.x*256 + threadIdx.x;
  int oc = (i / HW) & 31;
  float s = b1[oc];
  #pragma unroll
  for (int kg = 0; kg < 8; kg++) s += g_p[(size_t)kg*4*32*HW + i];
  g_o1[i] = fmaxf(s, 0.f);
}

// ---------------- K3: conv2 5x5 pad2 (32ch->26ch), split-K=2, bias in kg0; no relu
__global__ __launch_bounds__(256) void conv2_k(const float* __restrict__ wt2,
                                               const float* __restrict__ b2){
  __shared__ __align__(16) float in_sh[8][20][24];
  __shared__ __align__(16) float w_sh[8][25][32];
  int tile = blockIdx.x;
  int kg   = blockIdx.y;
  int b    = blockIdx.z;
  int row0 = (tile / 6) * 16, col0 = (tile % 6) * 16;
  int t = threadIdx.x;
  int og  = t >> 5;
  int pos = t & 31;
  int row = pos >> 1, x0 = (pos & 1)*8;

  float acc[8][4];
  #pragma unroll
  for (int j = 0; j < 8; j++)
    #pragma unroll
    for (int o = 0; o < 4; o++) acc[j][o] = 0.f;

  for (int cc = 0; cc < 2; cc++){
    __syncthreads();
    for (int idx = t; idx < 8*20*24; idx += 256){
      int i = idx / 480, rem = idx % 480;
      int r = rem / 24, c = rem % 24;
      int gr = row0 + r - 2, gc = col0 + c - 2;
      float v = 0.f;
      if ((unsigned)gr < 96u && (unsigned)gc < 96u){
        int ci = kg*16 + cc*8 + i;
        v = g_o1[(b*32 + ci)*HW + gr*96 + gc];
      }
      in_sh[i][r][c] = v;
    }
    for (int idx = t; idx < 8*25*32; idx += 256){
      int i = idx / 800, rem = idx % 800;
      int tap = rem / 32, oc = rem % 32;
      int ci = kg*16 + cc*8 + i;
      w_sh[i][tap][oc] = (oc < 26) ? wt2[oc*800 + ci*25 + tap] : 0.f;
    }
    __syncthreads();

    for (int i = 0; i < 8; i++){
      #pragma unroll
      for (int ky = 0; ky < 5; ky++){
        const float* rp = &in_sh[i][row + ky][x0];
        f32x4 s0 = *(const f32x4*)(rp);
        f32x4 s1 = *(const f32x4*)(rp + 4);
        f32x4 s2 = *(const f32x4*)(rp + 8);
        float seg[12] = {s0.x,s0.y,s0.z,s0.w, s1.x,s1.y,s1.z,s1.w, s2.x,s2.y,s2.z,s2.w};
        #pragma unroll
        for (int kx = 0; kx < 5; kx++){
          f32x4 wv = *(const f32x4*)&w_sh[i][ky*5 + kx][og*4];
          #pragma unroll
          for (int j = 0; j < 8; j++){
            float a = seg[kx + j];
            acc[j][0] += a*wv.x; acc[j][1] += a*wv.y;
            acc[j][2] += a*wv.z; acc[j][3] += a*wv.w;
          }
        }
      }
    }
  }

  int rg = row0 + row, cg = col0 + x0;
  #pragma unroll
  for (int o = 0; o < 4; o++){
    int slot = og*4 + o;
    if (slot < 26){
      float bias = (kg == 0) ? b2[slot] : 0.f;
      float* d = g_q + (size_t)kg*4*26*HW + ((size_t)(b*26 + slot))*HW + rg*96 + cg;
      #pragma unroll
      for (int j = 0; j < 8; j++) d[j] = acc[j][o] + bias;
    }
  }
}

// ---------------- K4: z-folded bilinear sampling -> A-matrix (bf16, A-frag swizzle)
// Channel-contiguous gathers from g_ht: thread = (px m, channel-quad cq).
__global__ __launch_bounds__(384) void sample_k(){
  __shared__ float cw[13][4][16];
  __shared__ int   co[13][4][16];
  int pt = blockIdx.x;            // 0..2303
  int t  = threadIdx.x;           // 0..383
  int b  = pt / 576;
  int p0 = (pt % 576) * 16;

  if (t < 208){
    int m = t/13, l = t%13;
    int p = p0 + m;
    const int NQ = 4*26*HW;
    float gx = fmaxf(g_q[(b*26 + l     )*HW + p] + g_q[NQ + (b*26 + l     )*HW + p], 0.f);
    float gy = fmaxf(g_q[(b*26 + 13 + l)*HW + p] + g_q[NQ + (b*26 + 13 + l)*HW + p], 0.f);
    float ix = gx * (96.f/95.f) - 0.5f;
    float iy = gy * (96.f/95.f) - 0.5f;
    float iz = (float)(l+1) * (13.f/12.f) - 0.5f;
    float z0 = floorf(iz);
    float zf = 0.f;
    #pragma unroll
    for (int dz = 0; dz < 2; dz++){
      float zc = z0 + (float)dz;
      float wz = 1.f - fabsf(iz - zc);
      if (zc >= 0.f && zc <= 12.f) zf += wz;
    }
    float x0f = floorf(ix), y0f = floorf(iy);
    #pragma unroll
    for (int dy = 0; dy < 2; dy++){
      float yc = y0f + (float)dy;
      float wy = 1.f - fabsf(iy - yc);
      bool  my = (yc >= 0.f) && (yc <= 95.f);
      int  yci = min(max((int)yc, 0), 95);
      #pragma unroll
      for (int dx = 0; dx < 2; dx++){
        float xc = x0f + (float)dx;
        float wx = 1.f - fabsf(ix - xc);
        bool  mx = (xc >= 0.f) && (xc <= 95.f);
        int  xci = min(max((int)xc, 0), 95);
        cw[l][dy*2+dx][m] = (mx && my) ? zf*wy*wx : 0.f;
        co[l][dy*2+dx][m] = yci*96 + xci;
      }
    }
  }
  __syncthreads();

  int m  = t & 15;                 // pixel in tile (lanes 0-15)
  int cq = t >> 4;                 // channel quad 0..23 (c0 = cq*4)
  int c0 = cq*4;
  const float* hb = g_ht + (size_t)b*HW*96 + c0;
  int kb3 = cq >> 3;               // which 32-block within l
  int kk  = (cq & 7)*4;            // offset within 32-block
  for (int l = 0; l < 13; l++){
    float w0 = cw[l][0][m], w1 = cw[l][1][m], w2 = cw[l][2][m], w3 = cw[l][3][m];
    int   o0 = co[l][0][m], o1 = co[l][1][m], o2 = co[l][2][m], o3 = co[l][3][m];
    f32x4 v0 = *(const f32x4*)(hb + (size_t)o0*96);
    f32x4 v1 = *(const f32x4*)(hb + (size_t)o1*96);
    f32x4 v2 = *(const f32x4*)(hb + (size_t)o2*96);
    f32x4 v3 = *(const f32x4*)(hb + (size_t)o3*96);
    f32x4 acc = w0*v0 + w1*v1 + w2*v2 + w3*v3;
    int kb = l*3 + kb3;
    u32x2 pk;
    pk.x = (uint)f2b(acc.x) | ((uint)f2b(acc.y) << 16);
    pk.y = (uint)f2b(acc.z) | ((uint)f2b(acc.w) << 16);
    *(u32x2*)&g_a[(size_t)(pt*39 + kb)*512 + m*32 + kk] = pk;
  }
}

// ---------------- K5: MFMA GEMM  [36864 x 1248] x [1248 x 288] -> g_urv (tile-major)
__global__ __launch_bounds__(256) void gemm_k(){
  __shared__ __align__(16) ushort Bsh[18*512];   // 18 KB: B[:,kb] tile
  int w    = threadIdx.x >> 6;
  int lane = threadIdx.x & 63;
  int pt   = blockIdx.x*4 + w;
  int nl   = lane & 15, quad = lane >> 4;
  int t    = threadIdx.x;

  f32x4 acc[18];
  #pragma unroll
  for (int nt = 0; nt < 18; nt++) acc[nt] = (f32x4){0.f,0.f,0.f,0.f};

  const s16x8* Ab = reinterpret_cast<const s16x8*>(g_a);
  const uint*  Bg = reinterpret_cast<const uint*>(g_b);
  uint* Bs32 = (uint*)Bsh;
  int foff = nl*4 + quad;

  for (int kb = 0; kb < 39; kb++){
    __syncthreads();
    #pragma unroll
    for (int u = 0; u < 18; u++){
      int idx = u*256 + t;
      Bs32[idx] = Bg[(idx >> 8)*39*256 + kb*256 + (idx & 255)];
    }
    __syncthreads();
    s16x8 a = Ab[(pt*39 + kb)*64 + foff];
    #pragma unroll
    for (int nt = 0; nt < 18; nt++){
      s16x8 bf = *(const s16x8*)&Bsh[nt*512 + nl*32 + quad*8];
      acc[nt] = __builtin_amdgcn_mfma_f32_16x16x32_bf16(a, bf, acc[nt], 0, 0, 0);
    }
  }

  float* dst = g_urv + (size_t)pt*4608;          // [pt][n=288][px=16]
  #pragma unroll
  for (int nt = 0; nt < 18; nt++)
    *(f32x4*)&dst[(nt*16 + nl)*16 + quad*4] = acc[nt];
}

// ---------------- K6: fused 3x3 convs on x + gating -> out
__global__ __launch_bounds__(256) void gate_k(const float* __restrict__ x,
                        const float* __restrict__ hp,
                        const float* __restrict__ uw, const float* __restrict__ ub,
                        const float* __restrict__ rw, const float* __restrict__ rb,
                        const float* __restrict__ vw, const float* __restrict__ vb,
                        const float* __restrict__ uwb, const float* __restrict__ rwb,
                        const float* __restrict__ vwb, float* __restrict__ out){
  int p  = blockIdx.x*256 + threadIdx.x;
  int oc = blockIdx.y;
  int b  = blockIdx.z;
  int h = p/96, w = p%96;
  float xU = ub[oc], xR = rb[oc], xV = vb[oc];
  const float* xb = x + b*8*HW;
  for (int ky = 0; ky < 3; ky++){
    int r = h+ky-1;
    if ((unsigned)r >= 96u) continue;
    for (int kx = 0; kx < 3; kx++){
      int c = w+kx-1;
      if ((unsigned)c >= 96u) continue;
      int off = r*96 + c;
      int wo  = ky*3 + kx;
      #pragma unroll
      for (int ic = 0; ic < 8; ic++){
        float a = xb[ic*HW + off];
        xU += a * uw[oc*72 + ic*9 + wo];
        xR += a * rw[oc*72 + ic*9 + wo];
        xV += a * vw[oc*72 + ic*9 + wo];
      }
    }
  }
  int pt = b*576 + (p >> 4), px = p & 15;
  const float* ur = g_urv + (size_t)pt*4608 + px;
  float gU = ur[(0*96 + oc)*16] + uwb[oc];
  float gR = ur[(1*96 + oc)*16] + rwb[oc];
  float gV = ur[(2*96 + oc)*16] + vwb[oc];
  float u = 1.f / (1.f + __expf(-(xU + gU)));
  float r = 1.f / (1.f + __expf(-(xR + gR)));
  float v = xV + r * gV;
  float oi = (v >= 0.f) ? v : 0.2f*v;
  float h0 = hp[(b*96 + oc)*HW + p];
  out[(b*96 + oc)*HW + p] = h0*u + oi*(1.f - u);
}

extern "C" void kernel_launch(void* const* d_in, const int* in_sizes, int n_in,
                              void* d_out, int out_size, void* d_ws, size_t ws_size,
                              hipStream_t stream){
  const float* x    = (const float*)d_in[0];
  const float* hp   = (const float*)d_in[1];
  const float* sw1  = (const float*)d_in[2];
  const float* sb1  = (const float*)d_in[3];
  const float* sw2  = (const float*)d_in[4];
  const float* sb2  = (const float*)d_in[5];
  const float* rw   = (const float*)d_in[6];
  const float* rb   = (const float*)d_in[7];
  const float* uw   = (const float*)d_in[8];
  const float* ub   = (const float*)d_in[9];
  const float* vw   = (const float*)d_in[10];
  const float* vb   = (const float*)d_in[11];
  const float* rww  = (const float*)d_in[12];
  const float* rwb  = (const float*)d_in[13];
  const float* uww  = (const float*)d_in[14];
  const float* uwb  = (const float*)d_in[15];
  const float* vww  = (const float*)d_in[16];
  const float* vwb  = (const float*)d_in[17];

  pack_b_k   <<<dim3((3*96*1248 + 255)/256), dim3(256), 0, stream>>>(uww, rww, vww);
  pack_w1_k  <<<dim3((104*25*32 + 255)/256), dim3(256), 0, stream>>>(sw1);
  transpose_k<<<dim3(288, 3, 4), dim3(256), 0, stream>>>(hp);
  conv1_k    <<<dim3(36, 8, 4), dim3(256), 0, stream>>>(x, hp);
  combine1_k <<<dim3(4*32*HW/256), dim3(256), 0, stream>>>(sb1);
  conv2_k    <<<dim3(36, 2, 4), dim3(256), 0, stream>>>(sw2, sb2);
  sample_k   <<<dim3(2304),     dim3(384), 0, stream>>>();
  gemm_k     <<<dim3(576),      dim3(256), 0, stream>>>();
  gate_k     <<<dim3(36, 96, 4), dim3(256), 0, stream>>>(x, hp,
               uw, ub, rw, rb, vw, vb, uwb, rwb, vwb, (float*)d_out);
}